// Round 4
// baseline (144.759 us; speedup 1.0000x reference)
//
#include <hip/hip_runtime.h>
#include <cstdint>

// =====================================================================
// MultiHeadAttention_84576495993495  (round 11)
//
// Algebraic collapse: einsum('bhqk,bhvo->bhvo', attn, v) sums attn over
// BOTH q and k; softmax rows sum to 1 -> factor is exactly S=2048.
//   final = x @ (2048*Wp@Wv)^T + (2048*Wp@bv + bp)
// Wq/bq/Wk/bk unused.
//
// R11: depth-3 counted-vmcnt pipeline (T4, m218: counted-vs-drain0 =
// +38-73% at same structure). R10 drained vmcnt(0) per iter (~400 cyc
// exposed x 16 iters); R9 counted but waited BEFORE compute (zero
// overlap) with 2 barriers/iter. Fix:
//   - BK=32, 4 LDS buffers (4 x 16 KB = 64 KB, same total as R10 ->
//     2 blocks/CU preserved), prefetch 3 tiles ahead.
//   - iter t: STAGE(t+3) -> ds_read(t) -> lgkmcnt(0) -> 16 MFMA ->
//     vmcnt(8)  [tile t+1 done; t+2,t+3 = 8 loads stay IN FLIGHT
//     across the barrier] -> ONE s_barrier. Tail drains 8->4->0.
//   - Tile t+1 issued at iter t-2: ~3 iters (~750+ cyc) to land ->
//     steady-state HBM latency fully hidden.
//   - WAR safe: STAGE(t+3) overwrites buf consumed at iter t-1, and is
//     issued only after the end-of-(t-1) barrier. (m152 race check.)
// Everything else identical to R10 (swizzle, XCD grouping, epilogues,
// prep, direct gemm1) -- pipeline is the only variable.
// =====================================================================

typedef unsigned short u16;
typedef __bf16 bf16x8 __attribute__((ext_vector_type(8)));
typedef float f32x4 __attribute__((ext_vector_type(4)));

__device__ __forceinline__ u16 f2bf(float f) {
  // round-to-nearest-even f32 -> bf16 bits (finite inputs)
  unsigned int u = __float_as_uint(f);
  u += 0x7fffu + ((u >> 16) & 1u);
  return (u16)(u >> 16);
}

// async global->LDS 16B copy; LDS dest = wave-uniform base + lane*16
__device__ __forceinline__ void load16(const void* g, void* l) {
  auto gp = (const __attribute__((address_space(1))) unsigned int*)(uintptr_t)g;
  auto lp = (__attribute__((address_space(3))) unsigned int*)(unsigned int)(uintptr_t)l;
  __builtin_amdgcn_global_load_lds(gp, lp, 16, 0, 0);
}

// ---------------------------------------------------------------------
// Fused prep. Block ranges:
//   [0,8192)      conv x   f32->bf16 (4 elem/thread)
//   [8192,9216)   conv Wp  f32->bf16
//   [9216,10240)  transpose+conv Wv -> Wv^T bf16 (32x32 tiles)
//   [10240,10496) cv[n] = 2048*dot(Wp[n,:],bv) + bp[n]
__global__ void k_prep(const float* __restrict__ x, const float* __restrict__ Wv,
                       const float* __restrict__ bv, const float* __restrict__ Wp,
                       const float* __restrict__ bp, u16* __restrict__ xb,
                       u16* __restrict__ wpb, u16* __restrict__ wvtb,
                       float* __restrict__ cv) {
  __shared__ float tile[32][33];
  const int b = blockIdx.x;
  const int tid = threadIdx.x;
  if (b < 9216) {  // conversions
    const float* src = (b < 8192) ? x : Wp;
    u16* dst = (b < 8192) ? xb : wpb;
    const long base = (long)((b < 8192) ? b : (b - 8192)) * 1024 + tid * 4;
    const float4 v = *(const float4*)(src + base);
    ushort4 o;
    o.x = f2bf(v.x); o.y = f2bf(v.y); o.z = f2bf(v.z); o.w = f2bf(v.w);
    *(ushort4*)(dst + base) = o;
  } else if (b < 10240) {  // transpose Wv
    const int tb = b - 9216;
    const int bi = (tb & 31) * 32;   // output row block (i)
    const int bj = (tb >> 5) * 32;   // output col block (j) = src row block
    const int tx = tid & 31;
    const int ty = tid >> 5;  // 0..7
    for (int r = ty; r < 32; r += 8)
      tile[r][tx] = Wv[(long)(bj + r) * 1024 + bi + tx];
    __syncthreads();
    for (int r = ty; r < 32; r += 8)
      wvtb[(long)(bi + r) * 1024 + bj + tx] = f2bf(tile[tx][r]);
  } else {  // bias fold
    const int row = (b - 10240) * 4 + (tid >> 6);
    const int lane = tid & 63;
    const float* w = Wp + (long)row * 1024;
    float s = 0.f;
    for (int j = lane; j < 1024; j += 64) s += w[j] * bv[j];
    for (int off = 32; off; off >>= 1) s += __shfl_down(s, off, 64);
    if (lane == 0) cv[row] = 2048.f * s + bp[row];
  }
}

// ---------------------------------------------------------------------
// NT bf16 GEMM: Out[M,N] = A[M,K] @ B[N,K]^T  (+bias or *2048->bf16)
// BM=BN=128, BK=32, 256 threads = 4 waves (2x2), each wave 64x64
// (4x4 MFMA acc, 16 MFMA per iter). Depth-3 counted-vmcnt pipeline.
// LDS swizzle (R8-verified): slot c of row r holds global chunk
// c ^ ((r>>1)&3); fragment ds_read_b128 aliases 2-way (free, m136).
// MODE 0: f32 out + bias, XCD-grouped 1-D grid (512 blocks).
// MODE 1: bf16 out * 2048 (weight product), plain 64-block grid.
template <int MODE>
__global__ __launch_bounds__(256) void k_gemm(
    const u16* __restrict__ A, const u16* __restrict__ B, void* __restrict__ OutV,
    const float* __restrict__ bias, int M, int N, int K) {
  __shared__ u16 As[4][128 * 32];  // 4 x 8 KB
  __shared__ u16 Bs[4][128 * 32];  // 4 x 8 KB

  const int tid = threadIdx.x;
  const int lane = tid & 63;
  const int wv = tid >> 6;
  const int waveM = (wv & 1) << 6;
  const int waveN = (wv >> 1) << 6;
  const int l15 = lane & 15;
  const int quad = lane >> 4;

  long bm, bn;
  if constexpr (MODE == 0) {
    // XCD grouping: xcd = id&7 owns 8 contiguous m-panels; a panel's 8
    // n-blocks are temporally adjacent on that XCD (B = 2 MB L2-fits).
    const int id = blockIdx.x;            // gridDim.x = (M/128)*(N/128)
    const int xcd = id & 7;
    const int j = id >> 3;
    const int nb = N >> 7;
    const int mPerXcd = M / 128 / 8;
    bm = (long)(xcd * mPerXcd + j / nb) * 128;
    bn = (long)(j % nb) * 128;
  } else {
    // 64 blocks: id&7 = n-block -> round-robin puts one n-column per
    // XCD; B panel reused within its XCD's L2.
    bm = (long)(blockIdx.x >> 3) * 128;
    bn = (long)(blockIdx.x & 7) * 128;
  }

  // Staging (R8-verified addressing): 2 calls each for A and B per
  // tile. Call r (0/1) of wave wv fills rows [(r*4+wv)*16, +16)
  // (1 KB = wave-uniform base + lane*16B). Lane l: row_local = l>>2,
  // LDS slot c = l&3, fetches global chunk cs = (l&3) ^ ((l>>3)&3).
  const int rl = lane >> 2;
  const int cs = (lane & 3) ^ ((lane >> 3) & 3);
  const u16* Ag0 = A + (bm + wv * 16 + rl) * (long)K + cs * 8;
  const u16* Bg0 = B + (bn + wv * 16 + rl) * (long)K + cs * 8;
  const long rowOff = 64 * (long)K;     // call r=1: +64 rows

  const int nT = K >> 5;  // # K-tiles (32 for K=1024)

  // stage tile tt into buffer tt&3 (4 x global_load_lds, 16B each)
  auto STAGE = [&](int tt) {
    const long k0 = (long)tt << 5;
    u16* Ad = &As[tt & 3][0] + (wv << 9);
    u16* Bd = &Bs[tt & 3][0] + (wv << 9);
    load16(Ag0 + k0, Ad);
    load16(Ag0 + rowOff + k0, Ad + 2048);
    load16(Bg0 + k0, Bd);
    load16(Bg0 + rowOff + k0, Bd + 2048);
  };

  const f32x4 zero = {0.f, 0.f, 0.f, 0.f};
  f32x4 acc[4][4];
#pragma unroll
  for (int i = 0; i < 4; ++i)
#pragma unroll
    for (int j = 0; j < 4; ++j) acc[i][j] = zero;

  // Fragment read: logical chunk quad of row (..+l15) sits at LDS slot
  // quad ^ ((l15>>1)&3)  (rows within a fragment group share (r>>1)&3).
  const int rq = quad ^ ((l15 >> 1) & 3);

  // ---- prologue: stage tiles 0..2; wait tile 0 (8 newer in flight) --
  STAGE(0); STAGE(1); STAGE(2);
  asm volatile("s_waitcnt vmcnt(8)" ::: "memory");
  __builtin_amdgcn_s_barrier();

  for (int t = 0; t < nT; ++t) {
    const int rem = nT - 1 - t;
    if (rem >= 3) STAGE(t + 3);
    __builtin_amdgcn_sched_barrier(0);  // stage issue stays ahead of reads

    const u16* Asb = &As[t & 3][0];
    const u16* Bsb = &Bs[t & 3][0];
    bf16x8 af[4], bg[4];
#pragma unroll
    for (int q = 0; q < 4; ++q) {
      af[q] = *(const bf16x8*)(Asb + (waveM + q * 16 + l15) * 32 + rq * 8);
      bg[q] = *(const bf16x8*)(Bsb + (waveN + q * 16 + l15) * 32 + rq * 8);
    }
    asm volatile("s_waitcnt lgkmcnt(0)" ::: "memory");
    __builtin_amdgcn_sched_barrier(0);  // rule #18: no MFMA hoist past wait

#pragma unroll
    for (int i = 0; i < 4; ++i)
#pragma unroll
      for (int j = 0; j < 4; ++j)
        acc[i][j] = __builtin_amdgcn_mfma_f32_16x16x32_bf16(af[i], bg[j],
                                                            acc[i][j], 0, 0, 0);

    if (rem > 0) {
      // wait ONLY tile t+1 (counted); newer tiles stay in flight
      if (rem >= 3)      asm volatile("s_waitcnt vmcnt(8)" ::: "memory");
      else if (rem == 2) asm volatile("s_waitcnt vmcnt(4)" ::: "memory");
      else               asm volatile("s_waitcnt vmcnt(0)" ::: "memory");
      __builtin_amdgcn_s_barrier();
    }
  }

  // epilogue: C/D layout col = lane&15, row = quad*4 + reg  [m89/m91]
#pragma unroll
  for (int i = 0; i < 4; ++i) {
    const long gm = bm + waveM + i * 16 + quad * 4;
#pragma unroll
    for (int j = 0; j < 4; ++j) {
      const long gn = bn + waveN + j * 16 + l15;
      if constexpr (MODE == 0) {
        float* outp = (float*)OutV;
        const float bb = bias[gn];
#pragma unroll
        for (int r = 0; r < 4; ++r)
          outp[(gm + r) * N + gn] = acc[i][j][r] + bb;
      } else {
        u16* outp = (u16*)OutV;
#pragma unroll
        for (int r = 0; r < 4; ++r)
          outp[(gm + r) * N + gn] = f2bf(acc[i][j][r] * 2048.f);
      }
    }
  }
}

// =====================================================================
extern "C" void kernel_launch(void* const* d_in, const int* in_sizes, int n_in,
                              void* d_out, int out_size, void* d_ws, size_t ws_size,
                              hipStream_t stream) {
  // setup_inputs order: x, Wq, bq, Wk, bk, Wv, bv, Wp, bp
  const float* x  = (const float*)d_in[0];
  const float* Wv = (const float*)d_in[5];
  const float* bv = (const float*)d_in[6];
  const float* Wp = (const float*)d_in[7];
  const float* bp = (const float*)d_in[8];

  char* ws = (char*)d_ws;
  u16* xb    = (u16*)(ws);                      // 16 MB  x bf16
  u16* wpb   = (u16*)(ws + (16u << 20));        //  2 MB  Wp bf16
  u16* wvtb  = (u16*)(ws + (18u << 20));        //  2 MB  Wv^T bf16
  u16* m2b   = (u16*)(ws + (20u << 20));        //  2 MB  M2 bf16
  float* cv  = (float*)(ws + (22u << 20));      //  4 KB  folded bias

  // 1) fused prep: conv x / conv Wp / transpose Wv / bias fold
  k_prep<<<10496, 256, 0, stream>>>(x, Wv, bv, Wp, bp, xb, wpb, wvtb, cv);

  // 2) M2 = bf16(2048 * Wp @ Wv)  (direct, 8x8 blocks, 32 iters each)
  k_gemm<1><<<64, 256, 0, stream>>>(wpb, wvtb, m2b, nullptr, 1024, 1024, 1024);

  // 3) out = x @ M2^T + cv  (64 panels x 8 n-blocks = 512, XCD-grouped)
  k_gemm<0><<<512, 256, 0, stream>>>(xb, m2b, d_out, cv, 8192, 1024, 1024);
}

// Round 5
// 139.088 us; speedup vs baseline: 1.0408x; 1.0408x over previous
//
#include <hip/hip_runtime.h>
#include <cstdint>

// =====================================================================
// MultiHeadAttention_84576495993495  (round 12)
//
// Algebraic collapse: einsum('bhqk,bhvo->bhvo', attn, v) sums attn over
// BOTH q and k; softmax rows sum to 1 -> factor is exactly S=2048.
//   final = x @ (2048*Wp@Wv)^T + (2048*Wp@bv + bp)
// Wq/bq/Wk/bk unused.
//
// R12 theory: R11 (counted depth-3) regressed vs R10 (drain-after-MFMA
// 2-phase) -- T4 needs 8-phase role-split to pay (regime gate). The
// real deficit vs m97's 874 TF is OCCUPANCY: m97 has 3-4 blocks/CU
// covering the drain; our 512-block grid gives 2 blocks/CU x 4 waves
// = 2 waves/SIMD. Fix at fixed grid: more waves per block.
//   - gemm0: 512 threads = 8 waves (wave grid 2Mx4N, tile 64x32,
//     acc 4x2). Same 128^2/BK=64/64KB-LDS/R10-schedule -> still 2
//     blocks/CU but 16 waves/CU = 4/SIMD (2x the drain cover).
//   - gemm1: 64x64 tiles -> 256 blocks (1/CU, full GPU) vs 64 blocks
//     (25% of GPU). Same schedule, 32 KB LDS.
// Schedule, swizzle, staging addressing, epilogues, prep: unchanged.
// =====================================================================

typedef unsigned short u16;
typedef __bf16 bf16x8 __attribute__((ext_vector_type(8)));
typedef float f32x4 __attribute__((ext_vector_type(4)));

__device__ __forceinline__ u16 f2bf(float f) {
  // round-to-nearest-even f32 -> bf16 bits (finite inputs)
  unsigned int u = __float_as_uint(f);
  u += 0x7fffu + ((u >> 16) & 1u);
  return (u16)(u >> 16);
}

// async global->LDS 16B copy; LDS dest = wave-uniform base + lane*16
__device__ __forceinline__ void load16(const void* g, void* l) {
  auto gp = (const __attribute__((address_space(1))) unsigned int*)(uintptr_t)g;
  auto lp = (__attribute__((address_space(3))) unsigned int*)(unsigned int)(uintptr_t)l;
  __builtin_amdgcn_global_load_lds(gp, lp, 16, 0, 0);
}

// ---------------------------------------------------------------------
// Fused prep. Block ranges:
//   [0,8192)      conv x   f32->bf16 (4 elem/thread)
//   [8192,9216)   conv Wp  f32->bf16
//   [9216,10240)  transpose+conv Wv -> Wv^T bf16 (32x32 tiles)
//   [10240,10496) cv[n] = 2048*dot(Wp[n,:],bv) + bp[n]
__global__ void k_prep(const float* __restrict__ x, const float* __restrict__ Wv,
                       const float* __restrict__ bv, const float* __restrict__ Wp,
                       const float* __restrict__ bp, u16* __restrict__ xb,
                       u16* __restrict__ wpb, u16* __restrict__ wvtb,
                       float* __restrict__ cv) {
  __shared__ float tile[32][33];
  const int b = blockIdx.x;
  const int tid = threadIdx.x;
  if (b < 9216) {  // conversions
    const float* src = (b < 8192) ? x : Wp;
    u16* dst = (b < 8192) ? xb : wpb;
    const long base = (long)((b < 8192) ? b : (b - 8192)) * 1024 + tid * 4;
    const float4 v = *(const float4*)(src + base);
    ushort4 o;
    o.x = f2bf(v.x); o.y = f2bf(v.y); o.z = f2bf(v.z); o.w = f2bf(v.w);
    *(ushort4*)(dst + base) = o;
  } else if (b < 10240) {  // transpose Wv
    const int tb = b - 9216;
    const int bi = (tb & 31) * 32;   // output row block (i)
    const int bj = (tb >> 5) * 32;   // output col block (j) = src row block
    const int tx = tid & 31;
    const int ty = tid >> 5;  // 0..7
    for (int r = ty; r < 32; r += 8)
      tile[r][tx] = Wv[(long)(bj + r) * 1024 + bi + tx];
    __syncthreads();
    for (int r = ty; r < 32; r += 8)
      wvtb[(long)(bi + r) * 1024 + bj + tx] = f2bf(tile[tx][r]);
  } else {  // bias fold
    const int row = (b - 10240) * 4 + (tid >> 6);
    const int lane = tid & 63;
    const float* w = Wp + (long)row * 1024;
    float s = 0.f;
    for (int j = lane; j < 1024; j += 64) s += w[j] * bv[j];
    for (int off = 32; off; off >>= 1) s += __shfl_down(s, off, 64);
    if (lane == 0) cv[row] = 2048.f * s + bp[row];
  }
}

// ---------------------------------------------------------------------
// NT bf16 GEMM: Out[M,N] = A[M,K] @ B[N,K]^T  (+bias or *2048->bf16)
// R10 schedule (verified best): 2-phase dbuf, per iter
//   STAGE(t+1) -> ds_read(t) -> lgkmcnt(0) -> MFMA -> vmcnt(0) -> bar.
// LDS: 64 u16/row, slot c of row r holds global chunk c ^ (r&7);
// fragment ds_read_b128 aliases 2-way (free, m136).
// MODE 0: BM=BN=128, 512 thr = 8 waves (2Mx4N, tile 64x32, acc 4x2),
//         f32 out + bias, XCD-grouped 512-block grid, 64 KB LDS.
// MODE 1: BM=BN=64, 256 thr = 4 waves (2x2, tile 32x32, acc 2x2),
//         bf16 out * 2048, 256-block grid (1/CU), 32 KB LDS.
template <int MODE>
__global__ __launch_bounds__(MODE == 0 ? 512 : 256) void k_gemm(
    const u16* __restrict__ A, const u16* __restrict__ B, void* __restrict__ OutV,
    const float* __restrict__ bias, int M, int N, int K) {
  constexpr int BM = (MODE == 0) ? 128 : 64;
  constexpr int BN = (MODE == 0) ? 128 : 64;
  constexpr int T  = (MODE == 0) ? 512 : 256;
  constexpr int WTM = (MODE == 0) ? 64 : 32;  // wave tile M
  constexpr int WTN = 32;                      // wave tile N
  constexpr int AccM = WTM / 16;               // 4 or 2
  constexpr int AccN = WTN / 16;               // 2
  constexpr int RPC = T / 8;                   // staged rows per call

  __shared__ u16 As[2][BM * 64];
  __shared__ u16 Bs[2][BN * 64];

  const int tid = threadIdx.x;
  const int lane = tid & 63;
  const int wv = tid >> 6;
  const int waveM = (wv & 1) * WTM;
  const int waveN = (wv >> 1) * WTN;
  const int l15 = lane & 15;
  const int quad = lane >> 4;

  long bm, bn;
  if constexpr (MODE == 0) {
    // XCD grouping: xcd = id&7 owns 8 contiguous m-panels; a panel's 8
    // n-blocks are temporally adjacent on that XCD (B = 2 MB L2-fits).
    const int id = blockIdx.x;            // gridDim.x = (M/128)*(N/128)
    const int xcd = id & 7;
    const int j = id >> 3;
    const int nb = N >> 7;
    const int mPerXcd = M / 128 / 8;
    bm = (long)(xcd * mPerXcd + j / nb) * 128;
    bn = (long)(j % nb) * 128;
  } else {
    // 256 blocks (16x16 of 64^2 tiles) -- full GPU; Wp/Wv panels all
    // L2-fit so no special locality mapping needed.
    bm = (long)(blockIdx.x >> 4) * 64;
    bn = (long)(blockIdx.x & 15) * 64;
  }

  // Staging: 2 calls each for A and B per tile; call r covers rows
  // [r*RPC, +RPC), dest = linear LDS base + tid*16B (wave-uniform base
  // + lane*16 per wave). Thread t: row = t>>3, LDS slot = t&7, global
  // chunk cs = (t&7) ^ (row&7)  [RPC multiple of 8 keeps row&7 = t>>3&7].
  const int rl = tid >> 3;
  const int cs = (tid & 7) ^ (rl & 7);
  const u16* Ag0 = A + (bm + rl) * (long)K + cs * 8;
  const u16* Bg0 = B + (bn + rl) * (long)K + cs * 8;

  const int nT = K >> 6;  // # K-tiles (16 for K=1024)

  // stage tile at k-offset k0 (elems) into buffer b (4 load16/thread)
  auto STAGE = [&](long k0, int b) {
    u16* Ad = &As[b][0] + tid * 8;
    u16* Bd = &Bs[b][0] + tid * 8;
    load16(Ag0 + k0, Ad);
    load16(Ag0 + k0 + (long)RPC * K, Ad + RPC * 64);
    load16(Bg0 + k0, Bd);
    load16(Bg0 + k0 + (long)RPC * K, Bd + RPC * 64);
  };

  const f32x4 zero = {0.f, 0.f, 0.f, 0.f};
  f32x4 acc[AccM][AccN];
#pragma unroll
  for (int i = 0; i < AccM; ++i)
#pragma unroll
    for (int j = 0; j < AccN; ++j) acc[i][j] = zero;

  // Fragment read slots (swizzled): logical chunk kk*4+quad of row
  // (..+l15) sits at slot ^ (l15&7)  (base rows are multiples of 8).
  const int rq0 = quad ^ (l15 & 7);        // kk = 0
  const int rq1 = (4 + quad) ^ (l15 & 7);  // kk = 1

  // ---- prologue: stage tile 0, drain once, barrier ----
  STAGE(0, 0);
  asm volatile("s_waitcnt vmcnt(0)" ::: "memory");
  __builtin_amdgcn_s_barrier();

  int cur = 0;
  for (int t = 0; t < nT; ++t) {
    const bool more = (t + 1) < nT;
    if (more) STAGE((long)(t + 1) << 6, cur ^ 1);
    __builtin_amdgcn_sched_barrier(0);  // keep stage issue ahead of reads

    const u16* Asb = &As[cur][0];
    const u16* Bsb = &Bs[cur][0];
    bf16x8 af[2][AccM], bg[2][AccN];
#pragma unroll
    for (int i = 0; i < AccM; ++i) {
      const int ra = (waveM + i * 16 + l15) * 64;
      af[0][i] = *(const bf16x8*)(Asb + ra + rq0 * 8);
      af[1][i] = *(const bf16x8*)(Asb + ra + rq1 * 8);
    }
#pragma unroll
    for (int j = 0; j < AccN; ++j) {
      const int rb = (waveN + j * 16 + l15) * 64;
      bg[0][j] = *(const bf16x8*)(Bsb + rb + rq0 * 8);
      bg[1][j] = *(const bf16x8*)(Bsb + rb + rq1 * 8);
    }
    asm volatile("s_waitcnt lgkmcnt(0)" ::: "memory");
    __builtin_amdgcn_sched_barrier(0);  // rule #18: no MFMA hoist past wait

#pragma unroll
    for (int kk = 0; kk < 2; ++kk)
#pragma unroll
      for (int i = 0; i < AccM; ++i)
#pragma unroll
        for (int j = 0; j < AccN; ++j)
          acc[i][j] = __builtin_amdgcn_mfma_f32_16x16x32_bf16(af[kk][i], bg[kk][j],
                                                              acc[i][j], 0, 0, 0);

    if (more) {
      // next tile's 8 loads had the whole read+MFMA phase to land
      asm volatile("s_waitcnt vmcnt(0)" ::: "memory");
      __builtin_amdgcn_s_barrier();
      cur ^= 1;
    }
  }

  // epilogue: C/D layout col = lane&15, row = quad*4 + reg  [m89/m91]
#pragma unroll
  for (int i = 0; i < AccM; ++i) {
    const long gm = bm + waveM + i * 16 + quad * 4;
#pragma unroll
    for (int j = 0; j < AccN; ++j) {
      const long gn = bn + waveN + j * 16 + l15;
      if constexpr (MODE == 0) {
        float* outp = (float*)OutV;
        const float bb = bias[gn];
#pragma unroll
        for (int r = 0; r < 4; ++r)
          outp[(gm + r) * N + gn] = acc[i][j][r] + bb;
      } else {
        u16* outp = (u16*)OutV;
#pragma unroll
        for (int r = 0; r < 4; ++r)
          outp[(gm + r) * N + gn] = f2bf(acc[i][j][r] * 2048.f);
      }
    }
  }
}

// =====================================================================
extern "C" void kernel_launch(void* const* d_in, const int* in_sizes, int n_in,
                              void* d_out, int out_size, void* d_ws, size_t ws_size,
                              hipStream_t stream) {
  // setup_inputs order: x, Wq, bq, Wk, bk, Wv, bv, Wp, bp
  const float* x  = (const float*)d_in[0];
  const float* Wv = (const float*)d_in[5];
  const float* bv = (const float*)d_in[6];
  const float* Wp = (const float*)d_in[7];
  const float* bp = (const float*)d_in[8];

  char* ws = (char*)d_ws;
  u16* xb    = (u16*)(ws);                      // 16 MB  x bf16
  u16* wpb   = (u16*)(ws + (16u << 20));        //  2 MB  Wp bf16
  u16* wvtb  = (u16*)(ws + (18u << 20));        //  2 MB  Wv^T bf16
  u16* m2b   = (u16*)(ws + (20u << 20));        //  2 MB  M2 bf16
  float* cv  = (float*)(ws + (22u << 20));      //  4 KB  folded bias

  // 1) fused prep: conv x / conv Wp / transpose Wv / bias fold
  k_prep<<<10496, 256, 0, stream>>>(x, Wv, bv, Wp, bp, xb, wpb, wvtb, cv);

  // 2) M2 = bf16(2048 * Wp @ Wv)  (64^2 tiles: 256 blocks, 16 iters)
  k_gemm<1><<<256, 256, 0, stream>>>(wpb, wvtb, m2b, nullptr, 1024, 1024, 1024);

  // 3) out = x @ M2^T + cv  (64 panels x 8 n-blocks = 512, XCD-grouped)
  k_gemm<0><<<512, 512, 0, stream>>>(xb, m2b, d_out, cv, 8192, 1024, 1024);
}